// Round 6
// baseline (239.768 us; speedup 1.0000x reference)
//
#include <hip/hip_runtime.h>
#include <hip/hip_bf16.h>

#define T_TOK 2048
#define E_DIM 1024
#define F_DIM 2048
#define N_EXP 8

typedef __attribute__((ext_vector_type(8))) short short8;
typedef __attribute__((ext_vector_type(4))) float f32x4;

__device__ __forceinline__ short bf2s(__hip_bfloat16 v) {
  union { __hip_bfloat16 b; short s; } u; u.b = v; return u.s;
}

__device__ __forceinline__ void gload_lds16(const void* g, void* l) {
  __builtin_amdgcn_global_load_lds((const __attribute__((address_space(1))) void*)g,
                                   (__attribute__((address_space(3))) void*)l, 16, 0, 0);
}

// ---------------- x fp32 -> bf16 ----------------
__global__ __launch_bounds__(256) void convert_x_kernel(const float* __restrict__ x,
                                                        __hip_bfloat16* __restrict__ xb) {
  size_t i = ((size_t)blockIdx.x * 256 + threadIdx.x) * 8;
  float4 a = *(const float4*)(x + i);
  float4 b = *(const float4*)(x + i + 4);
  short8 o;
  o[0] = bf2s(__float2bfloat16(a.x)); o[1] = bf2s(__float2bfloat16(a.y));
  o[2] = bf2s(__float2bfloat16(a.z)); o[3] = bf2s(__float2bfloat16(a.w));
  o[4] = bf2s(__float2bfloat16(b.x)); o[5] = bf2s(__float2bfloat16(b.y));
  o[6] = bf2s(__float2bfloat16(b.z)); o[7] = bf2s(__float2bfloat16(b.w));
  *(short8*)(xb + i) = o;
}

// ---------------- router: fp64 logits, top-2, softmax ----------------
__global__ __launch_bounds__(256) void router_kernel(const float* __restrict__ x,
                                                     const float* __restrict__ gk,
                                                     int* __restrict__ tk_e,
                                                     float* __restrict__ tk_p,
                                                     int* __restrict__ counts) {
  int w = threadIdx.x >> 6, l = threadIdx.x & 63;
  int t = blockIdx.x * 4 + w;
  const float* xr = x + (size_t)t * E_DIM;
  double acc[N_EXP];
#pragma unroll
  for (int n = 0; n < N_EXP; n++) acc[n] = 0.0;
  for (int j = 0; j < 16; j++) {
    int i = j * 64 + l;
    double xv = (double)xr[i];
    const float* g = gk + (size_t)i * N_EXP;
#pragma unroll
    for (int n = 0; n < N_EXP; n++) acc[n] += xv * (double)g[n];
  }
#pragma unroll
  for (int off = 32; off > 0; off >>= 1) {
#pragma unroll
    for (int n = 0; n < N_EXP; n++) acc[n] += __shfl_down(acc[n], off);
  }
  if (l == 0) {
    int e1 = 0; double v1 = acc[0];
    for (int n = 1; n < N_EXP; n++) if (acc[n] > v1) { v1 = acc[n]; e1 = n; }
    int e2 = -1; double v2 = -1e300;
    for (int n = 0; n < N_EXP; n++) if (n != e1 && acc[n] > v2) { v2 = acc[n]; e2 = n; }
    float ex = __expf((float)(v2 - v1));     // <= 1
    float p1 = 1.f / (1.f + ex);
    float p2 = ex / (1.f + ex);
    tk_e[t * 2 + 0] = e1; tk_p[t * 2 + 0] = p1;
    tk_e[t * 2 + 1] = e2; tk_p[t * 2 + 1] = p2;
    atomicAdd(&counts[e1], 1);
    atomicAdd(&counts[e2], 1);
  }
}

// ---------------- scan + permute, single block ----------------
__global__ __launch_bounds__(256) void scanperm_kernel(const int* __restrict__ tk_e,
                                                       const float* __restrict__ tk_p,
                                                       int* __restrict__ ctrl,
                                                       int* __restrict__ slot_tok,
                                                       float* __restrict__ slot_prob,
                                                       int* __restrict__ inv) {
  __shared__ int offs[8], cur[8];
  int tid = threadIdx.x;
  if (tid == 0) {
    int off = 0, idx = 0;
    for (int e = 0; e < N_EXP; e++) {
      offs[e] = off; cur[e] = 0;
      int c = ctrl[e];
      for (int m0 = 0; m0 < c; m0 += 128) {
        ctrl[32 + idx] = e;
        ctrl[96 + idx] = off + m0;
        ctrl[160 + idx] = (c - m0 < 128) ? (c - m0) : 128;
        idx++;
      }
      off += c;
    }
    ctrl[24] = idx;
  }
  __syncthreads();
  for (int g = tid; g < 2 * T_TOK; g += 256) {
    int e = tk_e[g];
    float p = tk_p[g];
    int pos = atomicAdd(&cur[e], 1);
    int slot = offs[e] + pos;
    slot_tok[slot] = g >> 1;
    slot_prob[slot] = p;
    inv[g] = slot;
  }
}

// ---------------- GEMM1: h = silu(X@w0)*(X@w1), fused fp32->bf16 B staging ----------------
// 512 thr (8 waves, 2m x 4n), BM=128 BN=128 BK=64, single-buffered LDS (48KB).
// B staging lane shape f2 x k8: float2 loads, b128 transposed writes (2-way banks).
// T14: B(t+1) loads issued after barrier2, land under compute(t).
__global__ __launch_bounds__(512, 4) void gemm1_kernel(const __hip_bfloat16* __restrict__ xb,
                                                       const float* __restrict__ w0,
                                                       const float* __restrict__ w1,
                                                       const int* __restrict__ ctrl,
                                                       const int* __restrict__ slot_tok,
                                                       __hip_bfloat16* __restrict__ h) {
  int lin = blockIdx.x;                         // 640 = 8 * 80
  int logical = (lin & 7) * 80 + (lin >> 3);    // XCD-chunked
  int mt = logical % 40;
  int fy = logical / 40;                        // 0..15
  if (mt >= ctrl[24]) return;
  int e = ctrl[32 + mt];
  int slot0 = ctrl[96 + mt];
  int rowsv = ctrl[160 + mt];
  int f0 = fy * 128;

  __shared__ alignas(16) short lA[128 * 64];
  __shared__ alignas(16) short lB0[128 * 64];
  __shared__ alignas(16) short lB1[128 * 64];

  int tid = threadIdx.x;
  int w = tid >> 6, l = tid & 63;
  int wm = w >> 2, wn = w & 3;
  int frow = l & 15, fk = l >> 4;

  // ---- A staging (bf16 global_load_lds, pre-swizzled source; proven 0-conflict) ----
  int r1 = tid >> 3;
  int kcA = ((tid & 7) ^ (r1 & 7)) * 8;
  int tokA1 = slot_tok[slot0 + r1];
  int tokA2 = slot_tok[slot0 + r1 + 64];
  const __hip_bfloat16* aS1 = xb + (size_t)tokA1 * E_DIM + kcA;
  const __hip_bfloat16* aS2 = xb + (size_t)tokA2 * E_DIM + kcA;

  // ---- B staging: lane (uf,uk): f = uf*2+{0,1}, k rows uk*8..+7 ----
  int uf = tid & 63, uk = tid >> 6;
  const float* b0s = w0 + ((size_t)e * E_DIM + uk * 8) * F_DIM + f0 + uf * 2;
  const float* b1s = w1 + ((size_t)e * E_DIM + uk * 8) * F_DIM + f0 + uf * 2;
  int elB = (uf * 2) * 64 + ((uk ^ (uf & 7)) * 8);   // j=0 row; j=1 adds 64

  float2 rB0[8], rB1[8];

  f32x4 zero4 = {0.f, 0.f, 0.f, 0.f};
  f32x4 acc0[4][2], acc1[4][2];
#pragma unroll
  for (int mi = 0; mi < 4; mi++)
#pragma unroll
    for (int ni = 0; ni < 2; ni++) { acc0[mi][ni] = zero4; acc1[mi][ni] = zero4; }

  auto loadB = [&](int t) {
    const float* p0 = b0s + (size_t)t * 64 * F_DIM;
    const float* p1 = b1s + (size_t)t * 64 * F_DIM;
#pragma unroll
    for (int rr = 0; rr < 8; ++rr) {
      rB0[rr] = *(const float2*)(p0 + (size_t)rr * F_DIM);
      rB1[rr] = *(const float2*)(p1 + (size_t)rr * F_DIM);
    }
  };
  auto writeB = [&]() {
#pragma unroll
    for (int j = 0; j < 2; ++j) {
      short8 q0, q1;
#pragma unroll
      for (int rr = 0; rr < 8; ++rr) {
        q0[rr] = bf2s(__float2bfloat16(j ? rB0[rr].y : rB0[rr].x));
        q1[rr] = bf2s(__float2bfloat16(j ? rB1[rr].y : rB1[rr].x));
      }
      *(short8*)&lB0[elB + j * 64] = q0;
      *(short8*)&lB1[elB + j * 64] = q1;
    }
  };

  loadB(0);

  const int NT = E_DIM / 64;
  for (int t = 0; t < NT; ++t) {
    __syncthreads();                    // previous compute done; LDS writable
    gload_lds16(aS1 + t * 64, &lA[w * 512]);
    gload_lds16(aS2 + t * 64, &lA[4096 + w * 512]);
    writeB();                           // regs(t) -> LDS
    __syncthreads();                    // drain A-DMA + ds_writes
    if (t + 1 < NT) loadB(t + 1);       // in flight under compute(t)
    __builtin_amdgcn_s_setprio(1);
#pragma unroll
    for (int ks = 0; ks < 2; ++ks) {
      short8 a[4], b0[2], b1[2];
#pragma unroll
      for (int mi = 0; mi < 4; ++mi) {
        int r = wm * 64 + mi * 16 + frow;
        a[mi] = *(const short8*)&lA[r * 64 + ((ks * 4 + fk) ^ (r & 7)) * 8];
      }
#pragma unroll
      for (int ni = 0; ni < 2; ++ni) {
        int n = wn * 32 + ni * 16 + frow;
        int off = n * 64 + (((ks * 4 + fk) ^ ((n >> 1) & 7))) * 8;
        b0[ni] = *(const short8*)&lB0[off];
        b1[ni] = *(const short8*)&lB1[off];
      }
#pragma unroll
      for (int mi = 0; mi < 4; ++mi)
#pragma unroll
        for (int ni = 0; ni < 2; ++ni) {
          acc0[mi][ni] = __builtin_amdgcn_mfma_f32_16x16x32_bf16(a[mi], b0[ni], acc0[mi][ni], 0, 0, 0);
          acc1[mi][ni] = __builtin_amdgcn_mfma_f32_16x16x32_bf16(a[mi], b1[ni], acc1[mi][ni], 0, 0, 0);
        }
    }
    __builtin_amdgcn_s_setprio(0);
  }

#pragma unroll
  for (int mi = 0; mi < 4; ++mi) {
#pragma unroll
    for (int j = 0; j < 4; ++j) {
      int r = wm * 64 + mi * 16 + fk * 4 + j;
      if (r < rowsv) {
        __hip_bfloat16* hr = h + (size_t)(slot0 + r) * F_DIM + f0 + wn * 32;
#pragma unroll
        for (int ni = 0; ni < 2; ++ni) {
          float v0 = acc0[mi][ni][j];
          float v1 = acc1[mi][ni][j];
          float s = (v0 / (1.f + __expf(-v0))) * v1;
          hr[ni * 16 + frow] = __float2bfloat16(s);
        }
      }
    }
  }
}

// ---------------- GEMM2: parts[slot] = p * (h @ wo), fused fp32 B staging ----------------
__global__ __launch_bounds__(512, 4) void gemm2_kernel(const __hip_bfloat16* __restrict__ h,
                                                       const float* __restrict__ wo,
                                                       const int* __restrict__ ctrl,
                                                       const float* __restrict__ slot_prob,
                                                       float* __restrict__ parts) {
  int lin = blockIdx.x;                         // 320 = 8 * 40
  int logical = (lin & 7) * 40 + (lin >> 3);
  int mt = logical % 40;
  int ey = logical / 40;                        // 0..7
  if (mt >= ctrl[24]) return;
  int e = ctrl[32 + mt];
  int slot0 = ctrl[96 + mt];
  int rowsv = ctrl[160 + mt];
  int e0 = ey * 128;

  __shared__ alignas(16) short lA[128 * 64];
  __shared__ alignas(16) short lB[128 * 64];

  int tid = threadIdx.x;
  int w = tid >> 6, l = tid & 63;
  int wm = w >> 2, wn = w & 3;
  int frow = l & 15, fk = l >> 4;

  int r1 = tid >> 3;
  int kcA = ((tid & 7) ^ (r1 & 7)) * 8;
  const __hip_bfloat16* aS1 = h + (size_t)(slot0 + r1) * F_DIM + kcA;
  const __hip_bfloat16* aS2 = aS1 + (size_t)64 * F_DIM;

  int ue = tid & 63, uk = tid >> 6;             // e-cols ue*2+{0,1}; f rows uk*8..+7
  const float* bs = wo + ((size_t)e * F_DIM + uk * 8) * E_DIM + e0 + ue * 2;
  int elB = (ue * 2) * 64 + ((uk ^ (ue & 7)) * 8);

  float2 rB[8];

  f32x4 zero4 = {0.f, 0.f, 0.f, 0.f};
  f32x4 acc[4][2];
#pragma unroll
  for (int mi = 0; mi < 4; mi++)
#pragma unroll
    for (int ni = 0; ni < 2; ni++) acc[mi][ni] = zero4;

  auto loadB = [&](int t) {
    const float* p = bs + (size_t)t * 64 * E_DIM;
#pragma unroll
    for (int rr = 0; rr < 8; ++rr)
      rB[rr] = *(const float2*)(p + (size_t)rr * E_DIM);
  };
  auto writeB = [&]() {
#pragma unroll
    for (int j = 0; j < 2; ++j) {
      short8 q;
#pragma unroll
      for (int rr = 0; rr < 8; ++rr)
        q[rr] = bf2s(__float2bfloat16(j ? rB[rr].y : rB[rr].x));
      *(short8*)&lB[elB + j * 64] = q;
    }
  };

  loadB(0);

  const int NT = F_DIM / 64;
  for (int t = 0; t < NT; ++t) {
    __syncthreads();
    gload_lds16(aS1 + t * 64, &lA[w * 512]);
    gload_lds16(aS2 + t * 64, &lA[4096 + w * 512]);
    writeB();
    __syncthreads();
    if (t + 1 < NT) loadB(t + 1);
    __builtin_amdgcn_s_setprio(1);
#pragma unroll
    for (int ks = 0; ks < 2; ++ks) {
      short8 a[4], b[2];
#pragma unroll
      for (int mi = 0; mi < 4; ++mi) {
        int r = wm * 64 + mi * 16 + frow;
        a[mi] = *(const short8*)&lA[r * 64 + ((ks * 4 + fk) ^ (r & 7)) * 8];
      }
#pragma unroll
      for (int ni = 0; ni < 2; ++ni) {
        int n = wn * 32 + ni * 16 + frow;
        b[ni] = *(const short8*)&lB[n * 64 + (((ks * 4 + fk) ^ ((n >> 1) & 7))) * 8];
      }
#pragma unroll
      for (int mi = 0; mi < 4; ++mi)
#pragma unroll
        for (int ni = 0; ni < 2; ++ni)
          acc[mi][ni] = __builtin_amdgcn_mfma_f32_16x16x32_bf16(a[mi], b[ni], acc[mi][ni], 0, 0, 0);
    }
    __builtin_amdgcn_s_setprio(0);
  }

#pragma unroll
  for (int mi = 0; mi < 4; ++mi) {
#pragma unroll
    for (int j = 0; j < 4; ++j) {
      int r = wm * 64 + mi * 16 + fk * 4 + j;
      if (r < rowsv) {
        int slot = slot0 + r;
        float p = slot_prob[slot];
        float* pr = parts + (size_t)slot * E_DIM + e0 + wn * 32;
#pragma unroll
        for (int ni = 0; ni < 2; ++ni)
          pr[ni * 16 + frow] = p * acc[mi][ni][j];
      }
    }
  }
}

// ---------------- combine: out[t] = parts[s1] + parts[s2] ----------------
__global__ __launch_bounds__(256) void combine_kernel(const float* __restrict__ parts,
                                                      const int* __restrict__ inv,
                                                      float* __restrict__ out) {
  int g = blockIdx.x * 256 + threadIdx.x;   // T_TOK*128
  int row = g >> 7, c = (g & 127) * 8;
  int s1 = inv[row * 2], s2 = inv[row * 2 + 1];
  const float4* p1 = (const float4*)(parts + (size_t)s1 * E_DIM + c);
  const float4* p2 = (const float4*)(parts + (size_t)s2 * E_DIM + c);
  float4 a0 = p1[0], a1 = p1[1], b0 = p2[0], b1 = p2[1];
  float4 o0 = {a0.x + b0.x, a0.y + b0.y, a0.z + b0.z, a0.w + b0.w};
  float4 o1 = {a1.x + b1.x, a1.y + b1.y, a1.z + b1.z, a1.w + b1.w};
  float4* op = (float4*)(out + (size_t)row * E_DIM + c);
  op[0] = o0; op[1] = o1;
}

extern "C" void kernel_launch(void* const* d_in, const int* in_sizes, int n_in,
                              void* d_out, int out_size, void* d_ws, size_t ws_size,
                              hipStream_t stream) {
  const float* x  = (const float*)d_in[0];
  const float* gk = (const float*)d_in[1];
  const float* w0 = (const float*)d_in[2];
  const float* w1 = (const float*)d_in[3];
  const float* wo = (const float*)d_in[4];
  float* out = (float*)d_out;
  char* ws = (char*)d_ws;

  const size_t SLOTS = 2 * T_TOK + 128;
  const size_t OFF_XB   = 0;
  const size_t OFF_H    = OFF_XB + (size_t)T_TOK * E_DIM * 2;
  const size_t OFF_PART = OFF_H + SLOTS * F_DIM * 2;
  const size_t OFF_STOK = OFF_PART + SLOTS * E_DIM * 4;
  const size_t OFF_SPRB = OFF_STOK + SLOTS * 4;
  const size_t OFF_TKE  = OFF_SPRB + SLOTS * 4;
  const size_t OFF_TKP  = OFF_TKE + (size_t)2 * T_TOK * 4;
  const size_t OFF_INV  = OFF_TKP + (size_t)2 * T_TOK * 4;
  const size_t OFF_CTRL = OFF_INV + (size_t)2 * T_TOK * 4;
  const size_t NEED     = OFF_CTRL + 1024;
  if (ws_size < NEED) return;

  __hip_bfloat16* xb   = (__hip_bfloat16*)(ws + OFF_XB);
  __hip_bfloat16* hbuf = (__hip_bfloat16*)(ws + OFF_H);
  float* parts     = (float*)(ws + OFF_PART);
  int*   slot_tok  = (int*)(ws + OFF_STOK);
  float* slot_prob = (float*)(ws + OFF_SPRB);
  int*   tk_e      = (int*)(ws + OFF_TKE);
  float* tk_p      = (float*)(ws + OFF_TKP);
  int*   inv       = (int*)(ws + OFF_INV);
  int*   ctrl      = (int*)(ws + OFF_CTRL);

  hipMemsetAsync(ctrl, 0, 1024, stream);
  hipMemsetAsync(slot_tok + 2 * T_TOK, 0, 128 * 4, stream);

  convert_x_kernel<<<(T_TOK * E_DIM) / (256 * 8), 256, 0, stream>>>(x, xb);
  router_kernel<<<T_TOK / 4, 256, 0, stream>>>(x, gk, tk_e, tk_p, ctrl);
  scanperm_kernel<<<1, 256, 0, stream>>>(tk_e, tk_p, ctrl, slot_tok, slot_prob, inv);
  gemm1_kernel<<<dim3(640), 512, 0, stream>>>(xb, w0, w1, ctrl, slot_tok, hbuf);
  gemm2_kernel<<<dim3(320), 512, 0, stream>>>(hbuf, wo, ctrl, slot_prob, parts);
  combine_kernel<<<(T_TOK * 128) / 256, 256, 0, stream>>>(parts, inv, out);
}